// Round 9
// baseline (720.057 us; speedup 1.0000x reference)
//
#include <hip/hip_runtime.h>

constexpr int FEAT = 128;

typedef __attribute__((ext_vector_type(8))) _Float16 f16x8;
typedef __attribute__((ext_vector_type(4))) float f32x4;

// ---------- fp16 helpers ----------
__device__ inline unsigned int halfpair(float a, float b) {
  unsigned short ua = __builtin_bit_cast(unsigned short, (_Float16)a);
  unsigned short ub = __builtin_bit_cast(unsigned short, (_Float16)b);
  return (unsigned int)ua | ((unsigned int)ub << 16);
}
__device__ inline unsigned short halfr(float a) {
  return __builtin_bit_cast(unsigned short, (_Float16)a);
}
__device__ inline float2 halfup(unsigned int u) {
  _Float16 lo = __builtin_bit_cast(_Float16, (unsigned short)(u & 0xffffu));
  _Float16 hi = __builtin_bit_cast(_Float16, (unsigned short)(u >> 16));
  return make_float2((float)lo, (float)hi);
}

// K-permutation for mfma 16x16x32 fragments (layout verified by passing rounds)
__device__ __host__ inline int kperm(int k) {
  return ((k >> 5) << 5) + (((k >> 2) & 3) << 3) + (((k >> 4) & 1) << 2) + (k & 3);
}

// ---------------- CSR build ----------------

__global__ void count_kernel(const int* __restrict__ dst, int* __restrict__ deg, int E) {
  int e = blockIdx.x * blockDim.x + threadIdx.x;
  if (e < E) atomicAdd(&deg[dst[e]], 1);
}

__global__ __launch_bounds__(256) void scan1_kernel(const int* __restrict__ in,
                                                    int* __restrict__ bsum, int n) {
  int base = blockIdx.x * 1024 + threadIdx.x * 4;
  int s = 0;
  if (base + 3 < n) {
    int4 v = *(const int4*)(in + base);
    s = v.x + v.y + v.z + v.w;
  } else {
#pragma unroll
    for (int j = 0; j < 4; j++)
      if (base + j < n) s += in[base + j];
  }
#pragma unroll
  for (int off = 1; off < 64; off <<= 1) s += __shfl_xor(s, off);
  __shared__ int ws[4];
  int lane = threadIdx.x & 63, wid = threadIdx.x >> 6;
  if (lane == 0) ws[wid] = s;
  __syncthreads();
  if (threadIdx.x == 0) bsum[blockIdx.x] = ws[0] + ws[1] + ws[2] + ws[3];
}

__global__ __launch_bounds__(64) void scan2_kernel(int* __restrict__ bsum, int nb) {
  int t = threadIdx.x;
  int v = (t < nb) ? bsum[t] : 0;
  int s = v;
#pragma unroll
  for (int off = 1; off < 64; off <<= 1) {
    int u = __shfl_up(s, off);
    if (t >= off) s += u;
  }
  if (t < nb) bsum[t] = s - v;
}

__global__ __launch_bounds__(256) void scan3_kernel(const int* __restrict__ in,
                                                    const int* __restrict__ boff,
                                                    int* __restrict__ out,
                                                    int* __restrict__ out2, int n) {
  int t = threadIdx.x;
  int base = blockIdx.x * 1024 + t * 4;
  int v0 = 0, v1 = 0, v2 = 0, v3 = 0;
  if (base + 3 < n) {
    int4 v = *(const int4*)(in + base);
    v0 = v.x; v1 = v.y; v2 = v.z; v3 = v.w;
  } else {
    if (base + 0 < n) v0 = in[base + 0];
    if (base + 1 < n) v1 = in[base + 1];
    if (base + 2 < n) v2 = in[base + 2];
  }
  int ts = v0 + v1 + v2 + v3;
  int s = ts;
  int lane = t & 63, wid = t >> 6;
#pragma unroll
  for (int off = 1; off < 64; off <<= 1) {
    int u = __shfl_up(s, off);
    if (lane >= off) s += u;
  }
  __shared__ int ws[4];
  if (lane == 63) ws[wid] = s;
  __syncthreads();
  int cross = 0;
#pragma unroll
  for (int i = 0; i < 4; i++)
    if (i < wid) cross += ws[i];
  int excl = boff[blockIdx.x] + cross + (s - ts);
  int o0 = excl, o1 = o0 + v0, o2 = o1 + v1, o3 = o2 + v2;
  if (base + 3 < n) {
    *(int4*)(out + base) = make_int4(o0, o1, o2, o3);
    *(int4*)(out2 + base) = make_int4(o0, o1, o2, o3);
  } else {
    if (base + 0 < n) { out[base + 0] = o0; out2[base + 0] = o0; }
    if (base + 1 < n) { out[base + 1] = o1; out2[base + 1] = o1; }
    if (base + 2 < n) { out[base + 2] = o2; out2[base + 2] = o2; }
  }
}

__global__ void fill_kernel(const int* __restrict__ src, const int* __restrict__ dst,
                            int* __restrict__ cursor, int* __restrict__ col, int E) {
  int e = blockIdx.x * blockDim.x + threadIdx.x;
  if (e < E) {
    int p = atomicAdd(&cursor[dst[e]], 1);
    col[p] = src[e];
  }
}

// ---------------- x fp32 -> fp16 ----------------

__global__ void convert_kernel(const float* __restrict__ x, unsigned short* __restrict__ xb,
                               int n4) {
  int idx = blockIdx.x * blockDim.x + threadIdx.x;
  if (idx >= n4) return;
  float4 v = ((const float4*)x)[idx];
  uint2 o;
  o.x = halfpair(v.x, v.y);
  o.y = halfpair(v.z, v.w);
  ((uint2*)xb)[idx] = o;
}

// ---------------- weights fp32 [k][n] -> fp16 LDS-image [n][swz(perm(k))] ----------------

__global__ void wconv_kernel(const float* __restrict__ w1, const float* __restrict__ fc1w,
                             unsigned short* __restrict__ dst) {
  int idx = blockIdx.x * blockDim.x + threadIdx.x;  // 5*16384
  if (idx >= 5 * FEAT * FEAT) return;
  int m = idx >> 14;
  int r = idx & (FEAT * FEAT - 1);
  int k = r >> 7, n = r & 127;
  float v = (m < 4) ? w1[idx] : fc1w[r];
  int p = kperm(k);
  int slot = p >> 3, e = p & 7;
  dst[m * FEAT * FEAT + n * FEAT + ((slot ^ (n & 7)) << 3) + e] = halfr(v);
}

// ---------------- aggregation: 4 nodes/wave (16 lanes x uint4), edges unroll-4 ----------------

__global__ void agg_kernel(const unsigned short* __restrict__ x, const int* __restrict__ rowptr,
                           const int* __restrict__ col, unsigned short* __restrict__ agg, int N) {
  int gid = blockIdx.x * blockDim.x + threadIdx.x;
  int wid = gid >> 6;
  int lane = threadIdx.x & 63;
  int node = wid * 4 + (lane >> 4);
  if (node >= N) return;
  int ln = lane & 15;
  const uint4* xr = (const uint4*)x;  // 16 uint4 per row
  uint4 s = xr[(size_t)node * 16 + ln];
  float2 t0 = halfup(s.x), t1 = halfup(s.y), t2 = halfup(s.z), t3 = halfup(s.w);
  float a0 = t0.x, a1 = t0.y, a2 = t1.x, a3 = t1.y;
  float a4 = t2.x, a5 = t2.y, a6 = t3.x, a7 = t3.y;
  float b0 = 0.f, b1 = 0.f, b2 = 0.f, b3 = 0.f;
  float b4 = 0.f, b5 = 0.f, b6 = 0.f, b7 = 0.f;
  int e0 = rowptr[node], e1 = rowptr[node + 1];
  int e = e0;
  for (; e + 3 < e1; e += 4) {
    int c0 = col[e], c1 = col[e + 1], c2 = col[e + 2], c3 = col[e + 3];
    uint4 v = xr[(size_t)c0 * 16 + ln];
    uint4 u = xr[(size_t)c1 * 16 + ln];
    uint4 w = xr[(size_t)c2 * 16 + ln];
    uint4 z = xr[(size_t)c3 * 16 + ln];
    float2 f;
    f = halfup(v.x); a0 += f.x; a1 += f.y;
    f = halfup(v.y); a2 += f.x; a3 += f.y;
    f = halfup(v.z); a4 += f.x; a5 += f.y;
    f = halfup(v.w); a6 += f.x; a7 += f.y;
    f = halfup(u.x); b0 += f.x; b1 += f.y;
    f = halfup(u.y); b2 += f.x; b3 += f.y;
    f = halfup(u.z); b4 += f.x; b5 += f.y;
    f = halfup(u.w); b6 += f.x; b7 += f.y;
    f = halfup(w.x); a0 += f.x; a1 += f.y;
    f = halfup(w.y); a2 += f.x; a3 += f.y;
    f = halfup(w.z); a4 += f.x; a5 += f.y;
    f = halfup(w.w); a6 += f.x; a7 += f.y;
    f = halfup(z.x); b0 += f.x; b1 += f.y;
    f = halfup(z.y); b2 += f.x; b3 += f.y;
    f = halfup(z.z); b4 += f.x; b5 += f.y;
    f = halfup(z.w); b6 += f.x; b7 += f.y;
  }
  for (; e < e1; e++) {
    uint4 v = xr[(size_t)col[e] * 16 + ln];
    float2 f;
    f = halfup(v.x); a0 += f.x; a1 += f.y;
    f = halfup(v.y); a2 += f.x; a3 += f.y;
    f = halfup(v.z); a4 += f.x; a5 += f.y;
    f = halfup(v.w); a6 += f.x; a7 += f.y;
  }
  a0 += b0; a1 += b1; a2 += b2; a3 += b3;
  a4 += b4; a5 += b5; a6 += b6; a7 += b7;
  uint4 o;
  o.x = halfpair(a0, a1);
  o.y = halfpair(a2, a3);
  o.z = halfpair(a4, a5);
  o.w = halfpair(a6, a7);
  ((uint4*)agg)[(size_t)node * 16 + ln] = o;
}

// ---------------- fp16 MFMA GEMM, 8 waves (2 row x 4 col), 128x128 tile ----------------
// mode 0: C = relu(A@W+b) store only
// mode 1: + BN col stats; LAST block reduces partials & folds BN into w2f/b2f (ticket idiom)
// mode 2: fused fc1+fc2: out[row] = dot(relu(A@W+b), fc2w) + fc2b (no C store)

__global__ __launch_bounds__(512, 4) void gemm_kernel(
    const unsigned short* __restrict__ A, const unsigned short* __restrict__ Wimg,
    const float* __restrict__ bias, unsigned short* __restrict__ C,
    float* __restrict__ pS, float* __restrict__ pQ, int N, int mode,
    const float* __restrict__ gamma, const float* __restrict__ beta,
    const float* __restrict__ w2, const float* __restrict__ b2,
    unsigned short* __restrict__ w2f, float* __restrict__ b2f, int* __restrict__ cntL,
    const float* __restrict__ fc2w, const float* __restrict__ fc2b,
    float* __restrict__ outp) {
  __shared__ unsigned short Al[FEAT * FEAT];  // 32KB
  __shared__ unsigned short Wl[FEAT * FEAT];  // 32KB
  __shared__ float ls[FEAT], lq[FEAT], red[FEAT];
  __shared__ int amLast;

  int tx = threadIdx.x;
  int row0 = blockIdx.x * FEAT;
  if (tx < FEAT) { ls[tx] = 0.f; lq[tx] = 0.f; red[tx] = 0.f; }

#pragma unroll
  for (int i = 0; i < 4; i++) {
    int idx = tx + i * 512;
    ((uint4*)Wl)[idx] = ((const uint4*)Wimg)[idx];
  }
#pragma unroll
  for (int i = 0; i < 8; i++) {
    int idx = tx + i * 512;  // 4096 uint2 chunks = 128 rows x 32
    int r = idx >> 5;
    int c = idx & 31;
    uint2 v = make_uint2(0u, 0u);
    if (row0 + r < N) v = ((const uint2*)(A + (size_t)(row0 + r) * FEAT))[c];
    int k0 = c << 2;
    int p0 = ((k0 >> 5) << 5) + (((k0 >> 2) & 3) << 3) + (((k0 >> 4) & 1) << 2);
    int slot = p0 >> 3, half4 = (p0 >> 2) & 1;
    *(uint2*)&Al[r * FEAT + ((slot ^ (r & 7)) << 3) + (half4 << 2)] = v;
  }
  __syncthreads();

  int w = tx >> 6;
  int l = tx & 63;
  int llo = l & 15, lhi = l >> 4;
  int wr = (w >> 2) * 64;       // 2 row groups
  int wc = (w & 3) * 32;        // 4 col groups

  f32x4 acc[4][2];
#pragma unroll
  for (int mi = 0; mi < 4; mi++)
#pragma unroll
    for (int nj = 0; nj < 2; nj++) acc[mi][nj] = (f32x4)(0.f);

#pragma unroll
  for (int s = 0; s < 4; s++) {
    f16x8 af[4], wf[2];
#pragma unroll
    for (int mi = 0; mi < 4; mi++) {
      int row = wr + mi * 16 + llo;
      af[mi] = *(const f16x8*)&Al[row * FEAT + ((((s << 2) + lhi) ^ (row & 7)) << 3)];
    }
#pragma unroll
    for (int nj = 0; nj < 2; nj++) {
      int n = wc + nj * 16 + llo;
      wf[nj] = *(const f16x8*)&Wl[n * FEAT + ((((s << 2) + lhi) ^ (n & 7)) << 3)];
    }
#pragma unroll
    for (int mi = 0; mi < 4; mi++)
#pragma unroll
      for (int nj = 0; nj < 2; nj++)
        acc[mi][nj] = __builtin_amdgcn_mfma_f32_16x16x32_f16(wf[nj], af[mi], acc[mi][nj], 0, 0, 0);
  }

  if (mode == 2) {
    // fused fc1+fc2: per-row dot with fc2w, no store of h
    float pr[4] = {0.f, 0.f, 0.f, 0.f};
#pragma unroll
    for (int nj = 0; nj < 2; nj++) {
      int colb = wc + nj * 16 + lhi * 4;
      float4 bb = *(const float4*)&bias[colb];
      float4 fw = *(const float4*)&fc2w[colb];
#pragma unroll
      for (int mi = 0; mi < 4; mi++) {
        f32x4 v = acc[mi][nj];
        float v0 = fmaxf(v[0] + bb.x, 0.f);
        float v1 = fmaxf(v[1] + bb.y, 0.f);
        float v2 = fmaxf(v[2] + bb.z, 0.f);
        float v3 = fmaxf(v[3] + bb.w, 0.f);
        pr[mi] += v0 * fw.x + v1 * fw.y + v2 * fw.z + v3 * fw.w;
      }
    }
#pragma unroll
    for (int mi = 0; mi < 4; mi++) {
      float r = pr[mi];
      r += __shfl_xor(r, 16);
      r += __shfl_xor(r, 32);
      if (lhi == 0) atomicAdd(&red[wr + mi * 16 + llo], r);
    }
    __syncthreads();
    if (tx < FEAT) {
      int row = row0 + tx;
      if (row < N) outp[row] = red[tx] + fc2b[0];
    }
    return;
  }

#pragma unroll
  for (int nj = 0; nj < 2; nj++) {
    int colb = wc + nj * 16 + lhi * 4;
    float4 bb = *(const float4*)&bias[colb];
    float ps[4] = {0.f, 0.f, 0.f, 0.f}, pq[4] = {0.f, 0.f, 0.f, 0.f};
#pragma unroll
    for (int mi = 0; mi < 4; mi++) {
      int row = row0 + wr + mi * 16 + llo;
      f32x4 v = acc[mi][nj];
      float v0 = fmaxf(v[0] + bb.x, 0.f);
      float v1 = fmaxf(v[1] + bb.y, 0.f);
      float v2 = fmaxf(v[2] + bb.z, 0.f);
      float v3 = fmaxf(v[3] + bb.w, 0.f);
      if (row < N) {
        *(uint2*)&C[(size_t)row * FEAT + colb] = make_uint2(halfpair(v0, v1), halfpair(v2, v3));
        ps[0] += v0; ps[1] += v1; ps[2] += v2; ps[3] += v3;
        pq[0] += v0 * v0; pq[1] += v1 * v1; pq[2] += v2 * v2; pq[3] += v3 * v3;
      }
    }
    if (mode == 1) {
#pragma unroll
      for (int r = 0; r < 4; r++) {
        float s2 = ps[r], q2 = pq[r];
#pragma unroll
        for (int off = 1; off < 16; off <<= 1) {
          s2 += __shfl_xor(s2, off);
          q2 += __shfl_xor(q2, off);
        }
        if (llo == 0) {
          atomicAdd(&ls[colb + r], s2);
          atomicAdd(&lq[colb + r], q2);
        }
      }
    }
  }

  if (mode == 1) {
    __syncthreads();
    if (tx < FEAT) {
      pS[(size_t)blockIdx.x * FEAT + tx] = ls[tx];
      pQ[(size_t)blockIdx.x * FEAT + tx] = lq[tx];
    }
    __threadfence();
    __syncthreads();
    if (tx == 0) amLast = (atomicAdd(cntL, 1) == (int)gridDim.x - 1);
    __syncthreads();
    if (amLast) {
      __threadfence();
      int nblk = gridDim.x;
      float* sred = (float*)Wl;        // reuse dead LDS
      float* qred = sred + 512;
      int c = tx & 127, q4 = tx >> 7;
      float S = 0.f, Q = 0.f;
      for (int b = q4; b < nblk; b += 4) {
        S += pS[(size_t)b * FEAT + c];
        Q += pQ[(size_t)b * FEAT + c];
      }
      sred[q4 * 128 + c] = S;
      qred[q4 * 128 + c] = Q;
      __syncthreads();
      float* sc = (float*)Al;
      float* sh = sc + 128;
      if (q4 == 0) {
        float Ss = sred[c] + sred[128 + c] + sred[256 + c] + sred[384 + c];
        float Qs = qred[c] + qred[128 + c] + qred[256 + c] + qred[384 + c];
        float invN = 1.0f / (float)N;
        float mean = Ss * invN;
        float var = Qs * invN - mean * mean;
        float rstd = rsqrtf(var + 1e-5f);
        float scale = gamma[c] * rstd;
        sc[c] = scale;
        sh[c] = beta[c] - mean * scale;
      }
      __syncthreads();
      float bacc = 0.f;
      for (int k = q4 * 32; k < q4 * 32 + 32; k++) {
        float wv = w2[k * FEAT + c];
        int p = kperm(k);
        int slot = p >> 3, e = p & 7;
        w2f[c * FEAT + ((slot ^ (c & 7)) << 3) + e] = halfr(sc[k] * wv);
        bacc += sh[k] * wv;
      }
      sred[q4 * 128 + c] = bacc;
      __syncthreads();
      if (q4 == 0) b2f[c] = b2[c] + sred[c] + sred[128 + c] + sred[256 + c] + sred[384 + c];
    }
  }
}

// ---------------- launch ----------------

extern "C" void kernel_launch(void* const* d_in, const int* in_sizes, int n_in,
                              void* d_out, int out_size, void* d_ws, size_t ws_size,
                              hipStream_t stream) {
  const float* x     = (const float*)d_in[0];
  const int*   ei    = (const int*)d_in[1];
  const float* w1    = (const float*)d_in[2];
  const float* b1    = (const float*)d_in[3];
  const float* gamma = (const float*)d_in[4];
  const float* beta  = (const float*)d_in[5];
  const float* w2    = (const float*)d_in[6];
  const float* b2    = (const float*)d_in[7];
  const float* fc1w  = (const float*)d_in[8];
  const float* fc1b  = (const float*)d_in[9];
  const float* fc2w  = (const float*)d_in[10];
  const float* fc2b  = (const float*)d_in[11];
  float* out = (float*)d_out;

  int N = in_sizes[0] / FEAT;  // 50000
  int E = in_sizes[1] / 2;     // 600000
  const int* srcI = ei;
  const int* dstI = ei + E;

  int gemmBlocks = (N + FEAT - 1) / FEAT;
  int n = N + 1;
  int nb = (n + 1023) / 1024;  // scan blocks (<= 64)

  size_t Nf = (size_t)N * FEAT;
  unsigned short* H = (unsigned short*)d_ws;       // fp16 activations (gather source)
  unsigned short* G = H + Nf;                      // fp16 work buffer
  unsigned short* wimg = G + Nf;                   // 5 fp16 weight images (w1 x4, fc1)
  unsigned short* w2f = wimg + 5 * FEAT * FEAT;    // folded gemm2 weight image
  float* b2f = (float*)(w2f + FEAT * FEAT);
  float* pS = b2f + FEAT;
  float* pQ = pS + (size_t)gemmBlocks * FEAT;
  int* cnt = (int*)(pQ + (size_t)gemmBlocks * FEAT);  // 8 ticket counters
  int* deg = cnt + 8;
  int* rowptr = deg + ((n + 3) & ~3);
  int* cursor = rowptr + ((n + 3) & ~3);
  int* bsum = cursor + ((n + 3) & ~3);
  int* col = bsum + 64;

  // CSR build (+ zero ticket counters)
  hipMemsetAsync(cnt, 0, (8 + n) * sizeof(int), stream);
  count_kernel<<<(E + 255) / 256, 256, 0, stream>>>(dstI, deg, E);
  scan1_kernel<<<nb, 256, 0, stream>>>(deg, bsum, n);
  scan2_kernel<<<1, 64, 0, stream>>>(bsum, nb);
  scan3_kernel<<<nb, 256, 0, stream>>>(deg, bsum, rowptr, cursor, n);
  fill_kernel<<<(E + 255) / 256, 256, 0, stream>>>(srcI, dstI, cursor, col, E);

  // fp16 conversions
  int n4 = (int)(Nf / 4);
  convert_kernel<<<(n4 + 255) / 256, 256, 0, stream>>>(x, H, n4);
  wconv_kernel<<<(5 * FEAT * FEAT + 255) / 256, 256, 0, stream>>>(w1, fc1w, wimg);

  int aggBlocks = (int)((((size_t)(N + 3) / 4) * 64 + 255) / 256);

  for (int l = 0; l < 4; l++) {
    agg_kernel<<<aggBlocks, 256, 0, stream>>>(H, rowptr, col, G, N);
    // gemm1 + stats + (last-block) BN fold into w2f/b2f
    gemm_kernel<<<gemmBlocks, 512, 0, stream>>>(
        G, wimg + (size_t)l * FEAT * FEAT, b1 + (size_t)l * FEAT, G, pS, pQ, N, 1,
        gamma + (size_t)l * FEAT, beta + (size_t)l * FEAT, w2 + (size_t)l * FEAT * FEAT,
        b2 + (size_t)l * FEAT, w2f, b2f, cnt + l, nullptr, nullptr, nullptr);
    // gemm2: G -> H (plain)
    gemm_kernel<<<gemmBlocks, 512, 0, stream>>>(
        G, w2f, b2f, H, nullptr, nullptr, N, 0,
        nullptr, nullptr, nullptr, nullptr, nullptr, nullptr, nullptr,
        nullptr, nullptr, nullptr);
  }

  // fused fc1+fc2: H -> out
  gemm_kernel<<<gemmBlocks, 512, 0, stream>>>(
      H, wimg + (size_t)4 * FEAT * FEAT, fc1b, nullptr, nullptr, nullptr, N, 2,
      nullptr, nullptr, nullptr, nullptr, nullptr, nullptr, nullptr,
      fc2w, fc2b, out);
}

// Round 10
// 393.338 us; speedup vs baseline: 1.8306x; 1.8306x over previous
//
#include <hip/hip_runtime.h>

constexpr int FEAT = 128;

typedef __attribute__((ext_vector_type(8))) _Float16 f16x8;
typedef __attribute__((ext_vector_type(4))) float f32x4;

// ---------- fp16 helpers ----------
__device__ inline unsigned int halfpair(float a, float b) {
  unsigned short ua = __builtin_bit_cast(unsigned short, (_Float16)a);
  unsigned short ub = __builtin_bit_cast(unsigned short, (_Float16)b);
  return (unsigned int)ua | ((unsigned int)ub << 16);
}
__device__ inline unsigned short halfr(float a) {
  return __builtin_bit_cast(unsigned short, (_Float16)a);
}
__device__ inline float2 halfup(unsigned int u) {
  _Float16 lo = __builtin_bit_cast(_Float16, (unsigned short)(u & 0xffffu));
  _Float16 hi = __builtin_bit_cast(_Float16, (unsigned short)(u >> 16));
  return make_float2((float)lo, (float)hi);
}

// K-permutation for mfma 16x16x32 fragments (layout verified by passing rounds)
__device__ __host__ inline int kperm(int k) {
  return ((k >> 5) << 5) + (((k >> 2) & 3) << 3) + (((k >> 4) & 1) << 2) + (k & 3);
}

// ---------------- CSR build ----------------

__global__ void count_kernel(const int* __restrict__ dst, int* __restrict__ deg, int E) {
  int e = blockIdx.x * blockDim.x + threadIdx.x;
  if (e < E) atomicAdd(&deg[dst[e]], 1);
}

__global__ __launch_bounds__(256) void scan1_kernel(const int* __restrict__ in,
                                                    int* __restrict__ bsum, int n) {
  int base = blockIdx.x * 1024 + threadIdx.x * 4;
  int s = 0;
  if (base + 3 < n) {
    int4 v = *(const int4*)(in + base);
    s = v.x + v.y + v.z + v.w;
  } else {
#pragma unroll
    for (int j = 0; j < 4; j++)
      if (base + j < n) s += in[base + j];
  }
#pragma unroll
  for (int off = 1; off < 64; off <<= 1) s += __shfl_xor(s, off);
  __shared__ int ws[4];
  int lane = threadIdx.x & 63, wid = threadIdx.x >> 6;
  if (lane == 0) ws[wid] = s;
  __syncthreads();
  if (threadIdx.x == 0) bsum[blockIdx.x] = ws[0] + ws[1] + ws[2] + ws[3];
}

__global__ __launch_bounds__(64) void scan2_kernel(int* __restrict__ bsum, int nb) {
  int t = threadIdx.x;
  int v = (t < nb) ? bsum[t] : 0;
  int s = v;
#pragma unroll
  for (int off = 1; off < 64; off <<= 1) {
    int u = __shfl_up(s, off);
    if (t >= off) s += u;
  }
  if (t < nb) bsum[t] = s - v;
}

__global__ __launch_bounds__(256) void scan3_kernel(const int* __restrict__ in,
                                                    const int* __restrict__ boff,
                                                    int* __restrict__ out,
                                                    int* __restrict__ out2, int n) {
  int t = threadIdx.x;
  int base = blockIdx.x * 1024 + t * 4;
  int v0 = 0, v1 = 0, v2 = 0, v3 = 0;
  if (base + 3 < n) {
    int4 v = *(const int4*)(in + base);
    v0 = v.x; v1 = v.y; v2 = v.z; v3 = v.w;
  } else {
    if (base + 0 < n) v0 = in[base + 0];
    if (base + 1 < n) v1 = in[base + 1];
    if (base + 2 < n) v2 = in[base + 2];
  }
  int ts = v0 + v1 + v2 + v3;
  int s = ts;
  int lane = t & 63, wid = t >> 6;
#pragma unroll
  for (int off = 1; off < 64; off <<= 1) {
    int u = __shfl_up(s, off);
    if (lane >= off) s += u;
  }
  __shared__ int ws[4];
  if (lane == 63) ws[wid] = s;
  __syncthreads();
  int cross = 0;
#pragma unroll
  for (int i = 0; i < 4; i++)
    if (i < wid) cross += ws[i];
  int excl = boff[blockIdx.x] + cross + (s - ts);
  int o0 = excl, o1 = o0 + v0, o2 = o1 + v1, o3 = o2 + v2;
  if (base + 3 < n) {
    *(int4*)(out + base) = make_int4(o0, o1, o2, o3);
    *(int4*)(out2 + base) = make_int4(o0, o1, o2, o3);
  } else {
    if (base + 0 < n) { out[base + 0] = o0; out2[base + 0] = o0; }
    if (base + 1 < n) { out[base + 1] = o1; out2[base + 1] = o1; }
    if (base + 2 < n) { out[base + 2] = o2; out2[base + 2] = o2; }
  }
}

__global__ void fill_kernel(const int* __restrict__ src, const int* __restrict__ dst,
                            int* __restrict__ cursor, int* __restrict__ col, int E) {
  int e = blockIdx.x * blockDim.x + threadIdx.x;
  if (e < E) {
    int p = atomicAdd(&cursor[dst[e]], 1);
    col[p] = src[e];
  }
}

// ---------------- x fp32 -> fp16 ----------------

__global__ void convert_kernel(const float* __restrict__ x, unsigned short* __restrict__ xb,
                               int n4) {
  int idx = blockIdx.x * blockDim.x + threadIdx.x;
  if (idx >= n4) return;
  float4 v = ((const float4*)x)[idx];
  uint2 o;
  o.x = halfpair(v.x, v.y);
  o.y = halfpair(v.z, v.w);
  ((uint2*)xb)[idx] = o;
}

// ---------------- weights fp32 [k][n] -> fp16 LDS-image [n][swz(perm(k))] ----------------

__global__ void wconv_kernel(const float* __restrict__ w1, const float* __restrict__ fc1w,
                             unsigned short* __restrict__ dst) {
  int idx = blockIdx.x * blockDim.x + threadIdx.x;  // 5*16384
  if (idx >= 5 * FEAT * FEAT) return;
  int m = idx >> 14;
  int r = idx & (FEAT * FEAT - 1);
  int k = r >> 7, n = r & 127;
  float v = (m < 4) ? w1[idx] : fc1w[r];
  int p = kperm(k);
  int slot = p >> 3, e = p & 7;
  dst[m * FEAT * FEAT + n * FEAT + ((slot ^ (n & 7)) << 3) + e] = halfr(v);
}

// ---------------- aggregation: 4 nodes/wave (16 lanes x uint4), edges unroll-4 ----------------

__global__ void agg_kernel(const unsigned short* __restrict__ x, const int* __restrict__ rowptr,
                           const int* __restrict__ col, unsigned short* __restrict__ agg, int N) {
  int gid = blockIdx.x * blockDim.x + threadIdx.x;
  int wid = gid >> 6;
  int lane = threadIdx.x & 63;
  int node = wid * 4 + (lane >> 4);
  if (node >= N) return;
  int ln = lane & 15;
  const uint4* xr = (const uint4*)x;  // 16 uint4 per row
  uint4 s = xr[(size_t)node * 16 + ln];
  float2 t0 = halfup(s.x), t1 = halfup(s.y), t2 = halfup(s.z), t3 = halfup(s.w);
  float a0 = t0.x, a1 = t0.y, a2 = t1.x, a3 = t1.y;
  float a4 = t2.x, a5 = t2.y, a6 = t3.x, a7 = t3.y;
  float b0 = 0.f, b1 = 0.f, b2 = 0.f, b3 = 0.f;
  float b4 = 0.f, b5 = 0.f, b6 = 0.f, b7 = 0.f;
  int e0 = rowptr[node], e1 = rowptr[node + 1];
  int e = e0;
  for (; e + 3 < e1; e += 4) {
    int c0 = col[e], c1 = col[e + 1], c2 = col[e + 2], c3 = col[e + 3];
    uint4 v = xr[(size_t)c0 * 16 + ln];
    uint4 u = xr[(size_t)c1 * 16 + ln];
    uint4 w = xr[(size_t)c2 * 16 + ln];
    uint4 z = xr[(size_t)c3 * 16 + ln];
    float2 f;
    f = halfup(v.x); a0 += f.x; a1 += f.y;
    f = halfup(v.y); a2 += f.x; a3 += f.y;
    f = halfup(v.z); a4 += f.x; a5 += f.y;
    f = halfup(v.w); a6 += f.x; a7 += f.y;
    f = halfup(u.x); b0 += f.x; b1 += f.y;
    f = halfup(u.y); b2 += f.x; b3 += f.y;
    f = halfup(u.z); b4 += f.x; b5 += f.y;
    f = halfup(u.w); b6 += f.x; b7 += f.y;
    f = halfup(w.x); a0 += f.x; a1 += f.y;
    f = halfup(w.y); a2 += f.x; a3 += f.y;
    f = halfup(w.z); a4 += f.x; a5 += f.y;
    f = halfup(w.w); a6 += f.x; a7 += f.y;
    f = halfup(z.x); b0 += f.x; b1 += f.y;
    f = halfup(z.y); b2 += f.x; b3 += f.y;
    f = halfup(z.z); b4 += f.x; b5 += f.y;
    f = halfup(z.w); b6 += f.x; b7 += f.y;
  }
  for (; e < e1; e++) {
    uint4 v = xr[(size_t)col[e] * 16 + ln];
    float2 f;
    f = halfup(v.x); a0 += f.x; a1 += f.y;
    f = halfup(v.y); a2 += f.x; a3 += f.y;
    f = halfup(v.z); a4 += f.x; a5 += f.y;
    f = halfup(v.w); a6 += f.x; a7 += f.y;
  }
  a0 += b0; a1 += b1; a2 += b2; a3 += b3;
  a4 += b4; a5 += b5; a6 += b6; a7 += b7;
  uint4 o;
  o.x = halfpair(a0, a1);
  o.y = halfpair(a2, a3);
  o.z = halfpair(a4, a5);
  o.w = halfpair(a6, a7);
  ((uint4*)agg)[(size_t)node * 16 + ln] = o;
}

// ---------------- fp16 MFMA GEMM, 8 waves (2 row x 4 col), 128x128 tile ----------------
// mode 0: C = relu(A@W+b) store only
// mode 1: + per-block BN col-stat partials (NO fence/ticket — stats reduced by next kernel)
// mode 2: fused fc1+fc2: out[row] = dot(relu(A@W+b), fc2w) + fc2b (no C store)

__global__ __launch_bounds__(512, 4) void gemm_kernel(
    const unsigned short* __restrict__ A, const unsigned short* __restrict__ Wimg,
    const float* __restrict__ bias, unsigned short* __restrict__ C,
    float* __restrict__ pS, float* __restrict__ pQ, int N, int mode,
    const float* __restrict__ fc2w, const float* __restrict__ fc2b,
    float* __restrict__ outp) {
  __shared__ unsigned short Al[FEAT * FEAT];  // 32KB
  __shared__ unsigned short Wl[FEAT * FEAT];  // 32KB
  __shared__ float ls[FEAT], lq[FEAT];

  int tx = threadIdx.x;
  int row0 = blockIdx.x * FEAT;
  if (tx < FEAT) { ls[tx] = 0.f; lq[tx] = 0.f; }

#pragma unroll
  for (int i = 0; i < 4; i++) {
    int idx = tx + i * 512;
    ((uint4*)Wl)[idx] = ((const uint4*)Wimg)[idx];
  }
#pragma unroll
  for (int i = 0; i < 8; i++) {
    int idx = tx + i * 512;  // 4096 uint2 chunks = 128 rows x 32
    int r = idx >> 5;
    int c = idx & 31;
    uint2 v = make_uint2(0u, 0u);
    if (row0 + r < N) v = ((const uint2*)(A + (size_t)(row0 + r) * FEAT))[c];
    int k0 = c << 2;
    int p0 = ((k0 >> 5) << 5) + (((k0 >> 2) & 3) << 3) + (((k0 >> 4) & 1) << 2);
    int slot = p0 >> 3, half4 = (p0 >> 2) & 1;
    *(uint2*)&Al[r * FEAT + ((slot ^ (r & 7)) << 3) + (half4 << 2)] = v;
  }
  __syncthreads();

  int w = tx >> 6;
  int l = tx & 63;
  int llo = l & 15, lhi = l >> 4;
  int wr = (w >> 2) * 64;       // 2 row groups
  int wc = (w & 3) * 32;        // 4 col groups

  f32x4 acc[4][2];
#pragma unroll
  for (int mi = 0; mi < 4; mi++)
#pragma unroll
    for (int nj = 0; nj < 2; nj++) acc[mi][nj] = (f32x4)(0.f);

#pragma unroll
  for (int s = 0; s < 4; s++) {
    f16x8 af[4], wf[2];
#pragma unroll
    for (int mi = 0; mi < 4; mi++) {
      int row = wr + mi * 16 + llo;
      af[mi] = *(const f16x8*)&Al[row * FEAT + ((((s << 2) + lhi) ^ (row & 7)) << 3)];
    }
#pragma unroll
    for (int nj = 0; nj < 2; nj++) {
      int n = wc + nj * 16 + llo;
      wf[nj] = *(const f16x8*)&Wl[n * FEAT + ((((s << 2) + lhi) ^ (n & 7)) << 3)];
    }
#pragma unroll
    for (int mi = 0; mi < 4; mi++)
#pragma unroll
      for (int nj = 0; nj < 2; nj++)
        acc[mi][nj] = __builtin_amdgcn_mfma_f32_16x16x32_f16(wf[nj], af[mi], acc[mi][nj], 0, 0, 0);
  }

  if (mode == 2) {
    // fused fc1+fc2: per-row dot with fc2w, no store of h
    float* red = ls;  // reuse
    float pr[4] = {0.f, 0.f, 0.f, 0.f};
#pragma unroll
    for (int nj = 0; nj < 2; nj++) {
      int colb = wc + nj * 16 + lhi * 4;
      float4 bb = *(const float4*)&bias[colb];
      float4 fw = *(const float4*)&fc2w[colb];
#pragma unroll
      for (int mi = 0; mi < 4; mi++) {
        f32x4 v = acc[mi][nj];
        float v0 = fmaxf(v[0] + bb.x, 0.f);
        float v1 = fmaxf(v[1] + bb.y, 0.f);
        float v2 = fmaxf(v[2] + bb.z, 0.f);
        float v3 = fmaxf(v[3] + bb.w, 0.f);
        pr[mi] += v0 * fw.x + v1 * fw.y + v2 * fw.z + v3 * fw.w;
      }
    }
#pragma unroll
    for (int mi = 0; mi < 4; mi++) {
      float r = pr[mi];
      r += __shfl_xor(r, 16);
      r += __shfl_xor(r, 32);
      if (lhi == 0) atomicAdd(&red[wr + mi * 16 + llo], r);
    }
    __syncthreads();
    if (tx < FEAT) {
      int row = row0 + tx;
      if (row < N) outp[row] = red[tx] + fc2b[0];
    }
    return;
  }

#pragma unroll
  for (int nj = 0; nj < 2; nj++) {
    int colb = wc + nj * 16 + lhi * 4;
    float4 bb = *(const float4*)&bias[colb];
    float ps[4] = {0.f, 0.f, 0.f, 0.f}, pq[4] = {0.f, 0.f, 0.f, 0.f};
#pragma unroll
    for (int mi = 0; mi < 4; mi++) {
      int row = row0 + wr + mi * 16 + llo;
      f32x4 v = acc[mi][nj];
      float v0 = fmaxf(v[0] + bb.x, 0.f);
      float v1 = fmaxf(v[1] + bb.y, 0.f);
      float v2 = fmaxf(v[2] + bb.z, 0.f);
      float v3 = fmaxf(v[3] + bb.w, 0.f);
      if (row < N) {
        *(uint2*)&C[(size_t)row * FEAT + colb] = make_uint2(halfpair(v0, v1), halfpair(v2, v3));
        ps[0] += v0; ps[1] += v1; ps[2] += v2; ps[3] += v3;
        pq[0] += v0 * v0; pq[1] += v1 * v1; pq[2] += v2 * v2; pq[3] += v3 * v3;
      }
    }
    if (mode == 1) {
#pragma unroll
      for (int r = 0; r < 4; r++) {
        float s2 = ps[r], q2 = pq[r];
#pragma unroll
        for (int off = 1; off < 16; off <<= 1) {
          s2 += __shfl_xor(s2, off);
          q2 += __shfl_xor(q2, off);
        }
        if (llo == 0) {
          atomicAdd(&ls[colb + r], s2);
          atomicAdd(&lq[colb + r], q2);
        }
      }
    }
  }
  if (mode == 1) {
    __syncthreads();
    if (tx < FEAT) {
      pS[(size_t)blockIdx.x * FEAT + tx] = ls[tx];
      pQ[(size_t)blockIdx.x * FEAT + tx] = lq[tx];
    }
  }
}

// ---------------- BN stats: one block per column, parallel partial reduce ----------------

__global__ __launch_bounds__(64) void stats_kernel(
    const float* __restrict__ pS, const float* __restrict__ pQ, int nblk,
    const float* __restrict__ gamma, const float* __restrict__ beta,
    float* __restrict__ scf, float* __restrict__ shf, int N) {
  int c = blockIdx.x;
  int ln = threadIdx.x;
  float s = 0.f, q = 0.f;
  for (int b = ln; b < nblk; b += 64) {
    s += pS[(size_t)b * FEAT + c];
    q += pQ[(size_t)b * FEAT + c];
  }
#pragma unroll
  for (int off = 32; off; off >>= 1) {
    s += __shfl_xor(s, off);
    q += __shfl_xor(q, off);
  }
  if (ln == 0) {
    float invN = 1.0f / (float)N;
    float mean = s * invN;
    float var = q * invN - mean * mean;
    float rstd = rsqrtf(var + 1e-5f);
    float scale = gamma[c] * rstd;
    scf[c] = scale;
    shf[c] = beta[c] - mean * scale;
  }
}

// ---------------- fold: one block per out-col, thread per k ----------------

__global__ __launch_bounds__(128) void fold2_kernel(
    const float* __restrict__ scf, const float* __restrict__ shf,
    const float* __restrict__ w2, const float* __restrict__ b2,
    unsigned short* __restrict__ w2f, float* __restrict__ b2f) {
  __shared__ float red[FEAT];
  int c = blockIdx.x;
  int k = threadIdx.x;
  float wv = w2[k * FEAT + c];
  int p = kperm(k);
  int slot = p >> 3, e = p & 7;
  w2f[c * FEAT + ((slot ^ (c & 7)) << 3) + e] = halfr(scf[k] * wv);
  red[k] = shf[k] * wv;
  __syncthreads();
#pragma unroll
  for (int off = 64; off > 0; off >>= 1) {
    if (k < off) red[k] += red[k + off];
    __syncthreads();
  }
  if (k == 0) b2f[c] = b2[c] + red[0];
}

// ---------------- launch ----------------

extern "C" void kernel_launch(void* const* d_in, const int* in_sizes, int n_in,
                              void* d_out, int out_size, void* d_ws, size_t ws_size,
                              hipStream_t stream) {
  const float* x     = (const float*)d_in[0];
  const int*   ei    = (const int*)d_in[1];
  const float* w1    = (const float*)d_in[2];
  const float* b1    = (const float*)d_in[3];
  const float* gamma = (const float*)d_in[4];
  const float* beta  = (const float*)d_in[5];
  const float* w2    = (const float*)d_in[6];
  const float* b2    = (const float*)d_in[7];
  const float* fc1w  = (const float*)d_in[8];
  const float* fc1b  = (const float*)d_in[9];
  const float* fc2w  = (const float*)d_in[10];
  const float* fc2b  = (const float*)d_in[11];
  float* out = (float*)d_out;

  int N = in_sizes[0] / FEAT;  // 50000
  int E = in_sizes[1] / 2;     // 600000
  const int* srcI = ei;
  const int* dstI = ei + E;

  int gemmBlocks = (N + FEAT - 1) / FEAT;
  int n = N + 1;
  int nb = (n + 1023) / 1024;  // scan blocks (<= 64)

  size_t Nf = (size_t)N * FEAT;
  unsigned short* H = (unsigned short*)d_ws;       // fp16 activations (gather source)
  unsigned short* G = H + Nf;                      // fp16 work buffer
  unsigned short* wimg = G + Nf;                   // 5 fp16 weight images (w1 x4, fc1)
  unsigned short* w2f = wimg + 5 * FEAT * FEAT;    // folded gemm2 weight image
  float* b2f = (float*)(w2f + FEAT * FEAT);
  float* scf = b2f + FEAT;
  float* shf = scf + FEAT;
  float* pS = shf + FEAT;
  float* pQ = pS + (size_t)gemmBlocks * FEAT;
  int* deg = (int*)(pQ + (size_t)gemmBlocks * FEAT);
  int* rowptr = deg + ((n + 3) & ~3);
  int* cursor = rowptr + ((n + 3) & ~3);
  int* bsum = cursor + ((n + 3) & ~3);
  int* col = bsum + 64;

  // CSR build
  hipMemsetAsync(deg, 0, n * sizeof(int), stream);
  count_kernel<<<(E + 255) / 256, 256, 0, stream>>>(dstI, deg, E);
  scan1_kernel<<<nb, 256, 0, stream>>>(deg, bsum, n);
  scan2_kernel<<<1, 64, 0, stream>>>(bsum, nb);
  scan3_kernel<<<nb, 256, 0, stream>>>(deg, bsum, rowptr, cursor, n);
  fill_kernel<<<(E + 255) / 256, 256, 0, stream>>>(srcI, dstI, cursor, col, E);

  // fp16 conversions
  int n4 = (int)(Nf / 4);
  convert_kernel<<<(n4 + 255) / 256, 256, 0, stream>>>(x, H, n4);
  wconv_kernel<<<(5 * FEAT * FEAT + 255) / 256, 256, 0, stream>>>(w1, fc1w, wimg);

  int aggBlocks = (int)((((size_t)(N + 3) / 4) * 64 + 255) / 256);

  for (int l = 0; l < 4; l++) {
    agg_kernel<<<aggBlocks, 256, 0, stream>>>(H, rowptr, col, G, N);
    gemm_kernel<<<gemmBlocks, 512, 0, stream>>>(
        G, wimg + (size_t)l * FEAT * FEAT, b1 + (size_t)l * FEAT, G, pS, pQ, N, 1,
        nullptr, nullptr, nullptr);
    stats_kernel<<<FEAT, 64, 0, stream>>>(pS, pQ, gemmBlocks, gamma + (size_t)l * FEAT,
                                          beta + (size_t)l * FEAT, scf, shf, N);
    fold2_kernel<<<FEAT, FEAT, 0, stream>>>(scf, shf, w2 + (size_t)l * FEAT * FEAT,
                                            b2 + (size_t)l * FEAT, w2f, b2f);
    gemm_kernel<<<gemmBlocks, 512, 0, stream>>>(
        G, w2f, b2f, H, nullptr, nullptr, N, 0, nullptr, nullptr, nullptr);
  }

  // fused fc1+fc2: H -> out
  gemm_kernel<<<gemmBlocks, 512, 0, stream>>>(
      H, wimg + (size_t)4 * FEAT * FEAT, fc1b, nullptr, nullptr, nullptr, N, 2,
      fc2w, fc2b, out);
}

// Round 11
// 386.260 us; speedup vs baseline: 1.8642x; 1.0183x over previous
//
#include <hip/hip_runtime.h>

constexpr int FEAT = 128;

typedef __attribute__((ext_vector_type(8))) _Float16 f16x8;
typedef __attribute__((ext_vector_type(4))) float f32x4;

// ---------- fp16 helpers ----------
__device__ inline unsigned int halfpair(float a, float b) {
  unsigned short ua = __builtin_bit_cast(unsigned short, (_Float16)a);
  unsigned short ub = __builtin_bit_cast(unsigned short, (_Float16)b);
  return (unsigned int)ua | ((unsigned int)ub << 16);
}
__device__ inline unsigned short halfr(float a) {
  return __builtin_bit_cast(unsigned short, (_Float16)a);
}
__device__ inline float2 halfup(unsigned int u) {
  _Float16 lo = __builtin_bit_cast(_Float16, (unsigned short)(u & 0xffffu));
  _Float16 hi = __builtin_bit_cast(_Float16, (unsigned short)(u >> 16));
  return make_float2((float)lo, (float)hi);
}

// K-permutation for mfma 16x16x32 fragments (layout verified by passing rounds)
__device__ __host__ inline int kperm(int k) {
  return ((k >> 5) << 5) + (((k >> 2) & 3) << 3) + (((k >> 4) & 1) << 2) + (k & 3);
}

// ---------------- fused prep: x->fp16 | weight images | degree count ----------------

__global__ __launch_bounds__(256) void prep_kernel(
    const float* __restrict__ x, unsigned short* __restrict__ xb, int n4,
    const float* __restrict__ w1, const float* __restrict__ fc1w,
    unsigned short* __restrict__ wimg,
    const int* __restrict__ dst, int* __restrict__ deg, int E, int B1, int B2) {
  int bid = blockIdx.x;
  if (bid < B1) {
    int idx = bid * 256 + threadIdx.x;
    if (idx < n4) {
      float4 v = ((const float4*)x)[idx];
      uint2 o;
      o.x = halfpair(v.x, v.y);
      o.y = halfpair(v.z, v.w);
      ((uint2*)xb)[idx] = o;
    }
  } else if (bid < B1 + B2) {
    int idx = (bid - B1) * 256 + threadIdx.x;
    if (idx < 5 * FEAT * FEAT) {
      int m = idx >> 14;
      int r = idx & (FEAT * FEAT - 1);
      int k = r >> 7, n = r & 127;
      float v = (m < 4) ? w1[idx] : fc1w[r];
      int p = kperm(k);
      int slot = p >> 3, e = p & 7;
      wimg[m * FEAT * FEAT + n * FEAT + ((slot ^ (n & 7)) << 3) + e] = halfr(v);
    }
  } else {
    int e = (bid - B1 - B2) * 256 + threadIdx.x;
    if (e < E) atomicAdd(&deg[dst[e]], 1);
  }
}

// ---------------- parallel 3-phase scan ----------------

__global__ __launch_bounds__(256) void scan1_kernel(const int* __restrict__ in,
                                                    int* __restrict__ bsum, int n) {
  int base = blockIdx.x * 1024 + threadIdx.x * 4;
  int s = 0;
  if (base + 3 < n) {
    int4 v = *(const int4*)(in + base);
    s = v.x + v.y + v.z + v.w;
  } else {
#pragma unroll
    for (int j = 0; j < 4; j++)
      if (base + j < n) s += in[base + j];
  }
#pragma unroll
  for (int off = 1; off < 64; off <<= 1) s += __shfl_xor(s, off);
  __shared__ int ws[4];
  int lane = threadIdx.x & 63, wid = threadIdx.x >> 6;
  if (lane == 0) ws[wid] = s;
  __syncthreads();
  if (threadIdx.x == 0) bsum[blockIdx.x] = ws[0] + ws[1] + ws[2] + ws[3];
}

__global__ __launch_bounds__(64) void scan2_kernel(int* __restrict__ bsum, int nb) {
  int t = threadIdx.x;
  int v = (t < nb) ? bsum[t] : 0;
  int s = v;
#pragma unroll
  for (int off = 1; off < 64; off <<= 1) {
    int u = __shfl_up(s, off);
    if (t >= off) s += u;
  }
  if (t < nb) bsum[t] = s - v;
}

__global__ __launch_bounds__(256) void scan3_kernel(const int* __restrict__ in,
                                                    const int* __restrict__ boff,
                                                    int* __restrict__ out,
                                                    int* __restrict__ out2, int n) {
  int t = threadIdx.x;
  int base = blockIdx.x * 1024 + t * 4;
  int v0 = 0, v1 = 0, v2 = 0, v3 = 0;
  if (base + 3 < n) {
    int4 v = *(const int4*)(in + base);
    v0 = v.x; v1 = v.y; v2 = v.z; v3 = v.w;
  } else {
    if (base + 0 < n) v0 = in[base + 0];
    if (base + 1 < n) v1 = in[base + 1];
    if (base + 2 < n) v2 = in[base + 2];
  }
  int ts = v0 + v1 + v2 + v3;
  int s = ts;
  int lane = t & 63, wid = t >> 6;
#pragma unroll
  for (int off = 1; off < 64; off <<= 1) {
    int u = __shfl_up(s, off);
    if (lane >= off) s += u;
  }
  __shared__ int ws[4];
  if (lane == 63) ws[wid] = s;
  __syncthreads();
  int cross = 0;
#pragma unroll
  for (int i = 0; i < 4; i++)
    if (i < wid) cross += ws[i];
  int excl = boff[blockIdx.x] + cross + (s - ts);
  int o0 = excl, o1 = o0 + v0, o2 = o1 + v1, o3 = o2 + v2;
  if (base + 3 < n) {
    *(int4*)(out + base) = make_int4(o0, o1, o2, o3);
    *(int4*)(out2 + base) = make_int4(o0, o1, o2, o3);
  } else {
    if (base + 0 < n) { out[base + 0] = o0; out2[base + 0] = o0; }
    if (base + 1 < n) { out[base + 1] = o1; out2[base + 1] = o1; }
    if (base + 2 < n) { out[base + 2] = o2; out2[base + 2] = o2; }
  }
}

__global__ void fill_kernel(const int* __restrict__ src, const int* __restrict__ dst,
                            int* __restrict__ cursor, int* __restrict__ col, int E) {
  int e = blockIdx.x * blockDim.x + threadIdx.x;
  if (e < E) {
    int p = atomicAdd(&cursor[dst[e]], 1);
    col[p] = src[e];
  }
}

// ---------------- aggregation: 4 nodes/wave (16 lanes x uint4), edges unroll-4 ----------------

__global__ void agg_kernel(const unsigned short* __restrict__ x, const int* __restrict__ rowptr,
                           const int* __restrict__ col, unsigned short* __restrict__ agg, int N) {
  int gid = blockIdx.x * blockDim.x + threadIdx.x;
  int wid = gid >> 6;
  int lane = threadIdx.x & 63;
  int node = wid * 4 + (lane >> 4);
  if (node >= N) return;
  int ln = lane & 15;
  const uint4* xr = (const uint4*)x;  // 16 uint4 per row
  uint4 s = xr[(size_t)node * 16 + ln];
  float2 t0 = halfup(s.x), t1 = halfup(s.y), t2 = halfup(s.z), t3 = halfup(s.w);
  float a0 = t0.x, a1 = t0.y, a2 = t1.x, a3 = t1.y;
  float a4 = t2.x, a5 = t2.y, a6 = t3.x, a7 = t3.y;
  float b0 = 0.f, b1 = 0.f, b2 = 0.f, b3 = 0.f;
  float b4 = 0.f, b5 = 0.f, b6 = 0.f, b7 = 0.f;
  int e0 = rowptr[node], e1 = rowptr[node + 1];
  int e = e0;
  for (; e + 3 < e1; e += 4) {
    int c0 = col[e], c1 = col[e + 1], c2 = col[e + 2], c3 = col[e + 3];
    uint4 v = xr[(size_t)c0 * 16 + ln];
    uint4 u = xr[(size_t)c1 * 16 + ln];
    uint4 w = xr[(size_t)c2 * 16 + ln];
    uint4 z = xr[(size_t)c3 * 16 + ln];
    float2 f;
    f = halfup(v.x); a0 += f.x; a1 += f.y;
    f = halfup(v.y); a2 += f.x; a3 += f.y;
    f = halfup(v.z); a4 += f.x; a5 += f.y;
    f = halfup(v.w); a6 += f.x; a7 += f.y;
    f = halfup(u.x); b0 += f.x; b1 += f.y;
    f = halfup(u.y); b2 += f.x; b3 += f.y;
    f = halfup(u.z); b4 += f.x; b5 += f.y;
    f = halfup(u.w); b6 += f.x; b7 += f.y;
    f = halfup(w.x); a0 += f.x; a1 += f.y;
    f = halfup(w.y); a2 += f.x; a3 += f.y;
    f = halfup(w.z); a4 += f.x; a5 += f.y;
    f = halfup(w.w); a6 += f.x; a7 += f.y;
    f = halfup(z.x); b0 += f.x; b1 += f.y;
    f = halfup(z.y); b2 += f.x; b3 += f.y;
    f = halfup(z.z); b4 += f.x; b5 += f.y;
    f = halfup(z.w); b6 += f.x; b7 += f.y;
  }
  for (; e < e1; e++) {
    uint4 v = xr[(size_t)col[e] * 16 + ln];
    float2 f;
    f = halfup(v.x); a0 += f.x; a1 += f.y;
    f = halfup(v.y); a2 += f.x; a3 += f.y;
    f = halfup(v.z); a4 += f.x; a5 += f.y;
    f = halfup(v.w); a6 += f.x; a7 += f.y;
  }
  a0 += b0; a1 += b1; a2 += b2; a3 += b3;
  a4 += b4; a5 += b5; a6 += b6; a7 += b7;
  uint4 o;
  o.x = halfpair(a0, a1);
  o.y = halfpair(a2, a3);
  o.z = halfpair(a4, a5);
  o.w = halfpair(a6, a7);
  ((uint4*)agg)[(size_t)node * 16 + ln] = o;
}

// ---------------- fp16 MFMA GEMM, 8 waves, 128x128 tile, W direct-from-global ----------------
// LDS = A image only (33KB) -> 3-4 blocks/CU. W image is L1/L2-hot (32KB shared by all blocks).
// mode 0: C = relu(A@W+b)
// mode 1: + per-block BN col-stat partials
// mode 2: fused fc1+fc2: out[row] = dot(relu(A@W+b), fc2w) + fc2b (no C store)

__global__ __launch_bounds__(512, 4) void gemm_kernel(
    const unsigned short* __restrict__ A, const unsigned short* __restrict__ Wimg,
    const float* __restrict__ bias, unsigned short* __restrict__ C,
    float* __restrict__ pS, float* __restrict__ pQ, int N, int mode,
    const float* __restrict__ fc2w, const float* __restrict__ fc2b,
    float* __restrict__ outp) {
  __shared__ unsigned short Al[FEAT * FEAT];  // 32KB
  __shared__ float ls[FEAT], lq[FEAT];

  int tx = threadIdx.x;
  int row0 = blockIdx.x * FEAT;
  if (tx < FEAT) { ls[tx] = 0.f; lq[tx] = 0.f; }

  // stage A: uint4 global loads, 2x uint2 LDS stores (perm+swizzle)
#pragma unroll
  for (int i = 0; i < 4; i++) {
    int idx = tx + i * 512;  // 2048 uint4 = 128 rows x 16
    int r = idx >> 4;
    int c = idx & 15;
    uint4 v = make_uint4(0u, 0u, 0u, 0u);
    if (row0 + r < N) v = ((const uint4*)(A + (size_t)(row0 + r) * FEAT))[c];
    int k0 = c << 3;
    int slotA = ((k0 >> 5) << 2) + ((k0 >> 2) & 3);  // even
    int sub = (k0 >> 4) & 1;
    int sw = r & 7;
    *(uint2*)&Al[r * FEAT + ((slotA ^ sw) << 3) + (sub << 2)] = make_uint2(v.x, v.y);
    *(uint2*)&Al[r * FEAT + (((slotA + 1) ^ sw) << 3) + (sub << 2)] = make_uint2(v.z, v.w);
  }
  __syncthreads();

  int w = tx >> 6;
  int l = tx & 63;
  int llo = l & 15, lhi = l >> 4;
  int wr = (w >> 2) * 64;       // 2 row groups
  int wc = (w & 3) * 32;        // 4 col groups

  // W fragment base: rows (wc+llo) and (wc+16+llo) of the image; same &7 since 16%8==0
  const unsigned short* w0p = Wimg + (size_t)(wc + llo) * FEAT;
  int m0 = (wc + llo) & 7;

  f32x4 acc[4][2];
#pragma unroll
  for (int mi = 0; mi < 4; mi++)
#pragma unroll
    for (int nj = 0; nj < 2; nj++) acc[mi][nj] = (f32x4)(0.f);

#pragma unroll
  for (int s = 0; s < 4; s++) {
    int so = (s << 2) + lhi;
    int woff = (so ^ m0) << 3;
    f16x8 wf0 = *(const f16x8*)&w0p[woff];
    f16x8 wf1 = *(const f16x8*)&w0p[16 * FEAT + woff];
    f16x8 af[4];
#pragma unroll
    for (int mi = 0; mi < 4; mi++) {
      int row = wr + mi * 16 + llo;
      af[mi] = *(const f16x8*)&Al[row * FEAT + ((so ^ (row & 7)) << 3)];
    }
#pragma unroll
    for (int mi = 0; mi < 4; mi++) {
      acc[mi][0] = __builtin_amdgcn_mfma_f32_16x16x32_f16(wf0, af[mi], acc[mi][0], 0, 0, 0);
      acc[mi][1] = __builtin_amdgcn_mfma_f32_16x16x32_f16(wf1, af[mi], acc[mi][1], 0, 0, 0);
    }
  }

  if (mode == 2) {
    // fused fc1+fc2: per-row dot with fc2w, no store of h
    float* red = ls;  // reuse
    float pr[4] = {0.f, 0.f, 0.f, 0.f};
#pragma unroll
    for (int nj = 0; nj < 2; nj++) {
      int colb = wc + nj * 16 + lhi * 4;
      float4 bb = *(const float4*)&bias[colb];
      float4 fw = *(const float4*)&fc2w[colb];
#pragma unroll
      for (int mi = 0; mi < 4; mi++) {
        f32x4 v = acc[mi][nj];
        float v0 = fmaxf(v[0] + bb.x, 0.f);
        float v1 = fmaxf(v[1] + bb.y, 0.f);
        float v2 = fmaxf(v[2] + bb.z, 0.f);
        float v3 = fmaxf(v[3] + bb.w, 0.f);
        pr[mi] += v0 * fw.x + v1 * fw.y + v2 * fw.z + v3 * fw.w;
      }
    }
#pragma unroll
    for (int mi = 0; mi < 4; mi++) {
      float r = pr[mi];
      r += __shfl_xor(r, 16);
      r += __shfl_xor(r, 32);
      if (lhi == 0) atomicAdd(&red[wr + mi * 16 + llo], r);
    }
    __syncthreads();
    if (tx < FEAT) {
      int row = row0 + tx;
      if (row < N) outp[row] = red[tx] + fc2b[0];
    }
    return;
  }

#pragma unroll
  for (int nj = 0; nj < 2; nj++) {
    int colb = wc + nj * 16 + lhi * 4;
    float4 bb = *(const float4*)&bias[colb];
    float ps[4] = {0.f, 0.f, 0.f, 0.f}, pq[4] = {0.f, 0.f, 0.f, 0.f};
#pragma unroll
    for (int mi = 0; mi < 4; mi++) {
      int row = row0 + wr + mi * 16 + llo;
      f32x4 v = acc[mi][nj];
      float v0 = fmaxf(v[0] + bb.x, 0.f);
      float v1 = fmaxf(v[1] + bb.y, 0.f);
      float v2 = fmaxf(v[2] + bb.z, 0.f);
      float v3 = fmaxf(v[3] + bb.w, 0.f);
      if (row < N) {
        *(uint2*)&C[(size_t)row * FEAT + colb] = make_uint2(halfpair(v0, v1), halfpair(v2, v3));
        ps[0] += v0; ps[1] += v1; ps[2] += v2; ps[3] += v3;
        pq[0] += v0 * v0; pq[1] += v1 * v1; pq[2] += v2 * v2; pq[3] += v3 * v3;
      }
    }
    if (mode == 1) {
#pragma unroll
      for (int r = 0; r < 4; r++) {
        float s2 = ps[r], q2 = pq[r];
#pragma unroll
        for (int off = 1; off < 16; off <<= 1) {
          s2 += __shfl_xor(s2, off);
          q2 += __shfl_xor(q2, off);
        }
        if (llo == 0) {
          atomicAdd(&ls[colb + r], s2);
          atomicAdd(&lq[colb + r], q2);
        }
      }
    }
  }
  if (mode == 1) {
    __syncthreads();
    if (tx < FEAT) {
      pS[(size_t)blockIdx.x * FEAT + tx] = ls[tx];
      pQ[(size_t)blockIdx.x * FEAT + tx] = lq[tx];
    }
  }
}

// ---------------- BN stats: one block per column, parallel partial reduce ----------------

__global__ __launch_bounds__(64) void stats_kernel(
    const float* __restrict__ pS, const float* __restrict__ pQ, int nblk,
    const float* __restrict__ gamma, const float* __restrict__ beta,
    float* __restrict__ scf, float* __restrict__ shf, int N) {
  int c = blockIdx.x;
  int ln = threadIdx.x;
  float s = 0.f, q = 0.f;
  for (int b = ln; b < nblk; b += 64) {
    s += pS[(size_t)b * FEAT + c];
    q += pQ[(size_t)b * FEAT + c];
  }
#pragma unroll
  for (int off = 32; off; off >>= 1) {
    s += __shfl_xor(s, off);
    q += __shfl_xor(q, off);
  }
  if (ln == 0) {
    float invN = 1.0f / (float)N;
    float mean = s * invN;
    float var = q * invN - mean * mean;
    float rstd = rsqrtf(var + 1e-5f);
    float scale = gamma[c] * rstd;
    scf[c] = scale;
    shf[c] = beta[c] - mean * scale;
  }
}

// ---------------- fold: one block per out-col, thread per k ----------------

__global__ __launch_bounds__(128) void fold2_kernel(
    const float* __restrict__ scf, const float* __restrict__ shf,
    const float* __restrict__ w2, const float* __restrict__ b2,
    unsigned short* __restrict__ w2f, float* __restrict__ b2f) {
  __shared__ float red[FEAT];
  int c = blockIdx.x;
  int k = threadIdx.x;
  float wv = w2[k * FEAT + c];
  int p = kperm(k);
  int slot = p >> 3, e = p & 7;
  w2f[c * FEAT + ((slot ^ (c & 7)) << 3) + e] = halfr(scf[k] * wv);
  red[k] = shf[k] * wv;
  __syncthreads();
#pragma unroll
  for (int off = 64; off > 0; off >>= 1) {
    if (k < off) red[k] += red[k + off];
    __syncthreads();
  }
  if (k == 0) b2f[c] = b2[c] + red[0];
}

// ---------------- launch ----------------

extern "C" void kernel_launch(void* const* d_in, const int* in_sizes, int n_in,
                              void* d_out, int out_size, void* d_ws, size_t ws_size,
                              hipStream_t stream) {
  const float* x     = (const float*)d_in[0];
  const int*   ei    = (const int*)d_in[1];
  const float* w1    = (const float*)d_in[2];
  const float* b1    = (const float*)d_in[3];
  const float* gamma = (const float*)d_in[4];
  const float* beta  = (const float*)d_in[5];
  const float* w2    = (const float*)d_in[6];
  const float* b2    = (const float*)d_in[7];
  const float* fc1w  = (const float*)d_in[8];
  const float* fc1b  = (const float*)d_in[9];
  const float* fc2w  = (const float*)d_in[10];
  const float* fc2b  = (const float*)d_in[11];
  float* out = (float*)d_out;

  int N = in_sizes[0] / FEAT;  // 50000
  int E = in_sizes[1] / 2;     // 600000
  const int* srcI = ei;
  const int* dstI = ei + E;

  int gemmBlocks = (N + FEAT - 1) / FEAT;
  int n = N + 1;
  int nb = (n + 1023) / 1024;  // scan blocks (<= 64)

  size_t Nf = (size_t)N * FEAT;
  unsigned short* H = (unsigned short*)d_ws;       // fp16 activations (gather source)
  unsigned short* G = H + Nf;                      // fp16 work buffer
  unsigned short* wimg = G + Nf;                   // 5 fp16 weight images (w1 x4, fc1)
  unsigned short* w2f = wimg + 5 * FEAT * FEAT;    // folded gemm2 weight image
  float* b2f = (float*)(w2f + FEAT * FEAT);
  float* scf = b2f + FEAT;
  float* shf = scf + FEAT;
  float* pS = shf + FEAT;
  float* pQ = pS + (size_t)gemmBlocks * FEAT;
  int* deg = (int*)(pQ + (size_t)gemmBlocks * FEAT);
  int* rowptr = deg + ((n + 3) & ~3);
  int* cursor = rowptr + ((n + 3) & ~3);
  int* bsum = cursor + ((n + 3) & ~3);
  int* col = bsum + 64;

  // prep: zero deg, then fused convert/wconv/count
  hipMemsetAsync(deg, 0, n * sizeof(int), stream);
  int n4 = (int)(Nf / 4);
  int B1 = (n4 + 255) / 256;
  int B2 = (5 * FEAT * FEAT + 255) / 256;
  int B3 = (E + 255) / 256;
  prep_kernel<<<B1 + B2 + B3, 256, 0, stream>>>(x, H, n4, w1, fc1w, wimg, dstI, deg, E, B1, B2);

  // CSR scan + fill
  scan1_kernel<<<nb, 256, 0, stream>>>(deg, bsum, n);
  scan2_kernel<<<1, 64, 0, stream>>>(bsum, nb);
  scan3_kernel<<<nb, 256, 0, stream>>>(deg, bsum, rowptr, cursor, n);
  fill_kernel<<<B3, 256, 0, stream>>>(srcI, dstI, cursor, col, E);

  int aggBlocks = (int)((((size_t)(N + 3) / 4) * 64 + 255) / 256);

  for (int l = 0; l < 4; l++) {
    agg_kernel<<<aggBlocks, 256, 0, stream>>>(H, rowptr, col, G, N);
    gemm_kernel<<<gemmBlocks, 512, 0, stream>>>(
        G, wimg + (size_t)l * FEAT * FEAT, b1 + (size_t)l * FEAT, G, pS, pQ, N, 1,
        nullptr, nullptr, nullptr);
    stats_kernel<<<FEAT, 64, 0, stream>>>(pS, pQ, gemmBlocks, gamma + (size_t)l * FEAT,
                                          beta + (size_t)l * FEAT, scf, shf, N);
    fold2_kernel<<<FEAT, FEAT, 0, stream>>>(scf, shf, w2 + (size_t)l * FEAT * FEAT,
                                            b2 + (size_t)l * FEAT, w2f, b2f);
    gemm_kernel<<<gemmBlocks, 512, 0, stream>>>(
        G, w2f, b2f, H, nullptr, nullptr, N, 0, nullptr, nullptr, nullptr);
  }

  // fused fc1+fc2: H -> out
  gemm_kernel<<<gemmBlocks, 512, 0, stream>>>(
      H, wimg + (size_t)4 * FEAT * FEAT, fc1b, nullptr, nullptr, nullptr, N, 2,
      fc2w, fc2b, out);
}